// Round 1
// baseline (2426.592 us; speedup 1.0000x reference)
//
#include <hip/hip_runtime.h>

#define N_BUS 200000
#define N_GEN 50000
#define E_BB 1600000
#define E_GB 400000
#define E_BG 400000
#define H 32

// ---------------------------------------------------------------------------
// Count in-degree per dst node (int atomics into a u32 buffer).
__global__ __launch_bounds__(256) void count_kernel(const int* __restrict__ dst,
                                                    int nE, unsigned* __restrict__ cnt) {
    int e = blockIdx.x * 256 + threadIdx.x;
    if (e < nE) atomicAdd(&cnt[dst[e]], 1u);
}

// In-place: u32 count -> f32 1/max(cnt,1) (bit pattern stored via u32).
__global__ __launch_bounds__(256) void inv_kernel(unsigned* buf, int n) {
    int i = blockIdx.x * 256 + threadIdx.x;
    if (i < n) {
        unsigned c = buf[i];
        float v = 1.0f / (float)(c > 1u ? c : 1u);
        buf[i] = __float_as_uint(v);
    }
}

// ---------------------------------------------------------------------------
// Fused node transform: for each node row x[i] (DIN feats):
//   out0[i] = x[i] @ W0                      (message features, relation 0)
//   out1[i] = x[i] @ W1                      (message features, relation 1; optional)
//   out2[i] = x[i] @ (W2a + W2b) + (ba + bb) (root term + summed biases)
// RELU_IN applies relu to x on load (layer-2 path). x may alias out2
// (in-place root write) -> x/out2 intentionally NOT __restrict__.
template <int DIN, bool HAS1, bool RELU_IN>
__global__ __launch_bounds__(256) void transform_kernel(
    const float* x, int n,
    const float* __restrict__ W0, float* __restrict__ out0,
    const float* __restrict__ W1, float* __restrict__ out1,
    const float* __restrict__ W2a, const float* __restrict__ W2b,
    const float* __restrict__ ba, const float* __restrict__ bb,
    float* out2)
{
    __shared__ float w0[DIN * H];
    __shared__ float w1[HAS1 ? DIN * H : 1];
    __shared__ float w2[DIN * H];
    __shared__ float bias[H];

    for (int idx = threadIdx.x; idx < DIN * H; idx += 256) {
        w0[idx] = W0[idx];
        if (HAS1) w1[idx] = W1[idx];
        w2[idx] = W2a[idx] + (W2b ? W2b[idx] : 0.0f);
    }
    if (threadIdx.x < H)
        bias[threadIdx.x] = ba[threadIdx.x] + (bb ? bb[threadIdx.x] : 0.0f);
    __syncthreads();

    int i = blockIdx.x * 256 + threadIdx.x;
    if (i >= n) return;

    const float4* xp = (const float4*)(x + (size_t)i * DIN);

    float a0[H], a1[HAS1 ? H : 1], a2[H];
#pragma unroll
    for (int j = 0; j < H; j++) {
        a0[j] = 0.0f;
        if (HAS1) a1[j] = 0.0f;
        a2[j] = bias[j];
    }

    for (int kk = 0; kk < DIN / 4; ++kk) {
        float4 xv = xp[kk];
        float xs[4] = {xv.x, xv.y, xv.z, xv.w};
#pragma unroll
        for (int q = 0; q < 4; q++) {
            float xk = RELU_IN ? fmaxf(xs[q], 0.0f) : xs[q];
            const int kb = (kk * 4 + q) * H;
#pragma unroll
            for (int j = 0; j < H; j++) {
                a0[j] = fmaf(xk, w0[kb + j], a0[j]);
                if (HAS1) a1[j] = fmaf(xk, w1[kb + j], a1[j]);
                a2[j] = fmaf(xk, w2[kb + j], a2[j]);
            }
        }
    }

    float4* o0 = (float4*)(out0 + (size_t)i * H);
#pragma unroll
    for (int j = 0; j < H / 4; j++)
        o0[j] = make_float4(a0[4 * j], a0[4 * j + 1], a0[4 * j + 2], a0[4 * j + 3]);
    if (HAS1) {
        float4* o1 = (float4*)(out1 + (size_t)i * H);
#pragma unroll
        for (int j = 0; j < H / 4; j++)
            o1[j] = make_float4(a1[4 * j], a1[4 * j + 1], a1[4 * j + 2], a1[4 * j + 3]);
    }
    float4* o2 = (float4*)(out2 + (size_t)i * H);
#pragma unroll
    for (int j = 0; j < H / 4; j++)
        o2[j] = make_float4(a2[4 * j], a2[4 * j + 1], a2[4 * j + 2], a2[4 * j + 3]);
}

// ---------------------------------------------------------------------------
// Edge scatter: acc[dst] += y[src] * inv[dst].  8 threads per edge, float4
// gather + 4 fp32 atomics each (device-scope atomicAdd -> L2).
__global__ __launch_bounds__(256) void scatter_kernel(
    const float* __restrict__ y, const int* __restrict__ src,
    const int* __restrict__ dst, const float* __restrict__ inv,
    float* acc, int nE)
{
    unsigned t = blockIdx.x * 256u + threadIdx.x;
    unsigned e = t >> 3;
    int j = (int)(t & 7u) * 4;
    if (e >= (unsigned)nE) return;
    int s = src[e], d = dst[e];
    float iv = inv[d];
    const float4 v = *(const float4*)(y + (size_t)s * H + j);
    float* a = acc + (size_t)d * H + j;
    atomicAdd(a + 0, v.x * iv);
    atomicAdd(a + 1, v.y * iv);
    atomicAdd(a + 2, v.z * iv);
    atomicAdd(a + 3, v.w * iv);
}

// ---------------------------------------------------------------------------
// Head: out = relu(h) @ (lin0_W @ linf_W) + (lin0_b @ linf_W + linf_b).
// Effective 32xDOUT matrix computed redundantly per block in LDS.
template <int DOUT>
__global__ __launch_bounds__(256) void final_kernel(
    const float* __restrict__ h, int n,
    const float* __restrict__ lin0W, const float* __restrict__ lin0b,
    const float* __restrict__ linfW, const float* __restrict__ linfb,
    float* __restrict__ out)
{
    __shared__ float we[H * DOUT];
    __shared__ float be[DOUT];
    if (threadIdx.x < H * DOUT) {
        int k = threadIdx.x / DOUT, c = threadIdx.x % DOUT;
        float s = 0.0f;
        for (int m = 0; m < H; m++) s += lin0W[k * H + m] * linfW[m * DOUT + c];
        we[threadIdx.x] = s;
    }
    if (threadIdx.x >= 128 && threadIdx.x < 128 + DOUT) {
        int c = threadIdx.x - 128;
        float s = linfb[c];
        for (int m = 0; m < H; m++) s += lin0b[m] * linfW[m * DOUT + c];
        be[c] = s;
    }
    __syncthreads();

    int i = blockIdx.x * 256 + threadIdx.x;
    if (i >= n) return;

    const float4* hp = (const float4*)(h + (size_t)i * H);
    float acc[DOUT];
#pragma unroll
    for (int c = 0; c < DOUT; c++) acc[c] = be[c];
#pragma unroll
    for (int q = 0; q < H / 4; q++) {
        float4 v = hp[q];
        float vs[4] = {fmaxf(v.x, 0.0f), fmaxf(v.y, 0.0f), fmaxf(v.z, 0.0f), fmaxf(v.w, 0.0f)};
#pragma unroll
        for (int r = 0; r < 4; r++) {
            int k = q * 4 + r;
#pragma unroll
            for (int c = 0; c < DOUT; c++) acc[c] = fmaf(vs[r], we[k * DOUT + c], acc[c]);
        }
    }
    if constexpr (DOUT == 4) {
        *(float4*)(out + (size_t)i * 4) = make_float4(acc[0], acc[1], acc[2], acc[3]);
    } else {
        *(float2*)(out + (size_t)i * 2) = make_float2(acc[0], acc[1]);
    }
}

// ---------------------------------------------------------------------------
extern "C" void kernel_launch(void* const* d_in, const int* in_sizes, int n_in,
                              void* d_out, int out_size, void* d_ws, size_t ws_size,
                              hipStream_t stream) {
    const float* x_bus = (const float*)d_in[0];
    const float* x_gen = (const float*)d_in[1];
    const int* src_bb = (const int*)d_in[2];
    const int* dst_bb = (const int*)d_in[3];
    const int* src_gb = (const int*)d_in[4];
    const int* dst_gb = (const int*)d_in[5];
    const int* src_bg = (const int*)d_in[6];
    const int* dst_bg = (const int*)d_in[7];
    const float* l1_bb_Wl = (const float*)d_in[8];
    const float* l1_bb_bl = (const float*)d_in[9];
    const float* l1_bb_Wr = (const float*)d_in[10];
    const float* l1_gb_Wl = (const float*)d_in[11];
    const float* l1_gb_bl = (const float*)d_in[12];
    const float* l1_gb_Wr = (const float*)d_in[13];
    const float* l1_bg_Wl = (const float*)d_in[14];
    const float* l1_bg_bl = (const float*)d_in[15];
    const float* l1_bg_Wr = (const float*)d_in[16];
    const float* l2_bb_Wl = (const float*)d_in[17];
    const float* l2_bb_bl = (const float*)d_in[18];
    const float* l2_bb_Wr = (const float*)d_in[19];
    const float* l2_gb_Wl = (const float*)d_in[20];
    const float* l2_gb_bl = (const float*)d_in[21];
    const float* l2_gb_Wr = (const float*)d_in[22];
    const float* l2_bg_Wl = (const float*)d_in[23];
    const float* l2_bg_bl = (const float*)d_in[24];
    const float* l2_bg_Wr = (const float*)d_in[25];
    const float* lin0_bus_W = (const float*)d_in[26];
    const float* lin0_bus_b = (const float*)d_in[27];
    const float* linf_bus_W = (const float*)d_in[28];
    const float* linf_bus_b = (const float*)d_in[29];
    const float* lin0_gen_W = (const float*)d_in[30];
    const float* lin0_gen_b = (const float*)d_in[31];
    const float* linf_gen_W = (const float*)d_in[32];
    const float* linf_gen_b = (const float*)d_in[33];

    // Workspace layout (all 256B aligned); total ~91.5 MB.
    char* ws = (char*)d_ws;
    size_t off = 0;
    auto alloc = [&](size_t bytes) {
        char* p = ws + off;
        off += (bytes + 255) & ~(size_t)255;
        return p;
    };
    unsigned* cnt_bb = (unsigned*)alloc((size_t)N_BUS * 4);
    unsigned* cnt_gb = (unsigned*)alloc((size_t)N_BUS * 4);
    unsigned* cnt_bg = (unsigned*)alloc((size_t)N_GEN * 4);
    float* y_bb = (float*)alloc((size_t)N_BUS * H * 4);
    float* y_bg = (float*)alloc((size_t)N_BUS * H * 4);
    float* y_gb = (float*)alloc((size_t)N_GEN * H * 4);
    float* h_bus = (float*)alloc((size_t)N_BUS * H * 4);
    float* h_gen = (float*)alloc((size_t)N_GEN * H * 4);
    const float* inv_bb = (const float*)cnt_bb;
    const float* inv_gb = (const float*)cnt_gb;
    const float* inv_bg = (const float*)cnt_bg;

    // Degrees -> reciprocals (graph is identical for both layers; do once).
    hipMemsetAsync(cnt_bb, 0, (size_t)N_BUS * 4, stream);
    hipMemsetAsync(cnt_gb, 0, (size_t)N_BUS * 4, stream);
    hipMemsetAsync(cnt_bg, 0, (size_t)N_GEN * 4, stream);
    count_kernel<<<(E_BB + 255) / 256, 256, 0, stream>>>(dst_bb, E_BB, cnt_bb);
    count_kernel<<<(E_GB + 255) / 256, 256, 0, stream>>>(dst_gb, E_GB, cnt_gb);
    count_kernel<<<(E_BG + 255) / 256, 256, 0, stream>>>(dst_bg, E_BG, cnt_bg);
    inv_kernel<<<(N_BUS + 255) / 256, 256, 0, stream>>>(cnt_bb, N_BUS);
    inv_kernel<<<(N_BUS + 255) / 256, 256, 0, stream>>>(cnt_gb, N_BUS);
    inv_kernel<<<(N_GEN + 255) / 256, 256, 0, stream>>>(cnt_bg, N_GEN);

    const int gb_bus = (N_BUS + 255) / 256;
    const int gb_gen = (N_GEN + 255) / 256;

    // ---- Layer 1 ----
    transform_kernel<64, true, false><<<gb_bus, 256, 0, stream>>>(
        x_bus, N_BUS, l1_bb_Wl, y_bb, l1_bg_Wl, y_bg,
        l1_bb_Wr, l1_gb_Wr, l1_bb_bl, l1_gb_bl, h_bus);
    transform_kernel<64, false, false><<<gb_gen, 256, 0, stream>>>(
        x_gen, N_GEN, l1_gb_Wl, y_gb, nullptr, nullptr,
        l1_bg_Wr, nullptr, l1_bg_bl, nullptr, h_gen);
    scatter_kernel<<<(E_BB * 8 + 255) / 256, 256, 0, stream>>>(y_bb, src_bb, dst_bb, inv_bb, h_bus, E_BB);
    scatter_kernel<<<(E_GB * 8 + 255) / 256, 256, 0, stream>>>(y_gb, src_gb, dst_gb, inv_gb, h_bus, E_GB);
    scatter_kernel<<<(E_BG * 8 + 255) / 256, 256, 0, stream>>>(y_bg, src_bg, dst_bg, inv_bg, h_gen, E_BG);

    // ---- Layer 2 (relu on load; root written in-place over h_*) ----
    transform_kernel<32, true, true><<<gb_bus, 256, 0, stream>>>(
        h_bus, N_BUS, l2_bb_Wl, y_bb, l2_bg_Wl, y_bg,
        l2_bb_Wr, l2_gb_Wr, l2_bb_bl, l2_gb_bl, h_bus);
    transform_kernel<32, false, true><<<gb_gen, 256, 0, stream>>>(
        h_gen, N_GEN, l2_gb_Wl, y_gb, nullptr, nullptr,
        l2_bg_Wr, nullptr, l2_bg_bl, nullptr, h_gen);
    scatter_kernel<<<(E_BB * 8 + 255) / 256, 256, 0, stream>>>(y_bb, src_bb, dst_bb, inv_bb, h_bus, E_BB);
    scatter_kernel<<<(E_GB * 8 + 255) / 256, 256, 0, stream>>>(y_gb, src_gb, dst_gb, inv_gb, h_bus, E_GB);
    scatter_kernel<<<(E_BG * 8 + 255) / 256, 256, 0, stream>>>(y_bg, src_bg, dst_bg, inv_bg, h_gen, E_BG);

    // ---- Head ----
    final_kernel<4><<<gb_bus, 256, 0, stream>>>(h_bus, N_BUS, lin0_bus_W, lin0_bus_b,
                                                linf_bus_W, linf_bus_b, (float*)d_out);
    final_kernel<2><<<gb_gen, 256, 0, stream>>>(h_gen, N_GEN, lin0_gen_W, lin0_gen_b,
                                                linf_gen_W, linf_gen_b, (float*)d_out + (size_t)N_BUS * 4);
}

// Round 2
// 792.589 us; speedup vs baseline: 3.0616x; 3.0616x over previous
//
#include <hip/hip_runtime.h>

#define N_BUS 200000
#define N_GEN 50000
#define E_BB 1600000
#define E_GB 400000
#define E_BG 400000
#define H 32

// ---------------------------------------------------------------------------
// Histogram: rs[dst]++ (int atomics).
__global__ __launch_bounds__(256) void count_kernel(const int* __restrict__ dst,
                                                    int nE, unsigned* __restrict__ rs) {
    int e = blockIdx.x * 256 + threadIdx.x;
    if (e < nE) atomicAdd(&rs[dst[e]], 1u);
}

// ---------------------------------------------------------------------------
// Exclusive scan over rs[0..n), 1024 elems/block (256 thr x 4).
__global__ __launch_bounds__(256) void scan_local_kernel(unsigned* __restrict__ rs, int n,
                                                         unsigned* __restrict__ bsum) {
    __shared__ unsigned sh[256];
    int tid = threadIdx.x;
    int base = blockIdx.x * 1024 + tid * 4;
    unsigned v[4];
    unsigned ts = 0;
#pragma unroll
    for (int q = 0; q < 4; q++) {
        v[q] = (base + q < n) ? rs[base + q] : 0u;
        ts += v[q];
    }
    sh[tid] = ts;
    __syncthreads();
#pragma unroll
    for (int d = 1; d < 256; d <<= 1) {
        unsigned t = (tid >= d) ? sh[tid - d] : 0u;
        __syncthreads();
        sh[tid] += t;
        __syncthreads();
    }
    unsigned run = sh[tid] - ts;  // exclusive offset of this thread within block
#pragma unroll
    for (int q = 0; q < 4; q++) {
        if (base + q < n) rs[base + q] = run;
        run += v[q];
    }
    if (tid == 255) bsum[blockIdx.x] = sh[255];
}

// Single-block exclusive scan of per-block sums (nb <= 256).
__global__ __launch_bounds__(256) void scan_bsums_kernel(unsigned* __restrict__ bsum, int nb) {
    __shared__ unsigned sh[256];
    int tid = threadIdx.x;
    unsigned ts = (tid < nb) ? bsum[tid] : 0u;
    sh[tid] = ts;
    __syncthreads();
#pragma unroll
    for (int d = 1; d < 256; d <<= 1) {
        unsigned t = (tid >= d) ? sh[tid - d] : 0u;
        __syncthreads();
        sh[tid] += t;
        __syncthreads();
    }
    if (tid < nb) bsum[tid] = sh[tid] - ts;
}

__global__ __launch_bounds__(256) void scan_add_kernel(unsigned* __restrict__ rs, int n,
                                                       const unsigned* __restrict__ bsum) {
    int base = blockIdx.x * 1024 + threadIdx.x * 4;
    unsigned off = bsum[blockIdx.x];
#pragma unroll
    for (int q = 0; q < 4; q++)
        if (base + q < n) rs[base + q] += off;
}

// ---------------------------------------------------------------------------
// Bucket edges: rs acts as cursor (exclusive start -> becomes inclusive end).
__global__ __launch_bounds__(256) void bucket_kernel(const int* __restrict__ src,
                                                     const int* __restrict__ dst, int nE,
                                                     unsigned* __restrict__ rs,
                                                     unsigned* __restrict__ esrc) {
    int e = blockIdx.x * 256 + threadIdx.x;
    if (e < nE) {
        unsigned pos = atomicAdd(&rs[dst[e]], 1u);
        esrc[pos] = (unsigned)src[e];
    }
}

// ---------------------------------------------------------------------------
// Fused node transform (unchanged from R1): y0 = x@W0, y1 = x@W1 (opt),
// h = x@(W2a+W2b) + (ba+bb).  RELU_IN applies relu(x) on load.
template <int DIN, bool HAS1, bool RELU_IN>
__global__ __launch_bounds__(256) void transform_kernel(
    const float* x, int n,
    const float* __restrict__ W0, float* __restrict__ out0,
    const float* __restrict__ W1, float* __restrict__ out1,
    const float* __restrict__ W2a, const float* __restrict__ W2b,
    const float* __restrict__ ba, const float* __restrict__ bb,
    float* out2)
{
    __shared__ float w0[DIN * H];
    __shared__ float w1[HAS1 ? DIN * H : 1];
    __shared__ float w2[DIN * H];
    __shared__ float bias[H];

    for (int idx = threadIdx.x; idx < DIN * H; idx += 256) {
        w0[idx] = W0[idx];
        if (HAS1) w1[idx] = W1[idx];
        w2[idx] = W2a[idx] + (W2b ? W2b[idx] : 0.0f);
    }
    if (threadIdx.x < H)
        bias[threadIdx.x] = ba[threadIdx.x] + (bb ? bb[threadIdx.x] : 0.0f);
    __syncthreads();

    int i = blockIdx.x * 256 + threadIdx.x;
    if (i >= n) return;

    const float4* xp = (const float4*)(x + (size_t)i * DIN);

    float a0[H], a1[HAS1 ? H : 1], a2[H];
#pragma unroll
    for (int j = 0; j < H; j++) {
        a0[j] = 0.0f;
        if (HAS1) a1[j] = 0.0f;
        a2[j] = bias[j];
    }

    for (int kk = 0; kk < DIN / 4; ++kk) {
        float4 xv = xp[kk];
        float xs[4] = {xv.x, xv.y, xv.z, xv.w};
#pragma unroll
        for (int q = 0; q < 4; q++) {
            float xk = RELU_IN ? fmaxf(xs[q], 0.0f) : xs[q];
            const int kb = (kk * 4 + q) * H;
#pragma unroll
            for (int j = 0; j < H; j++) {
                a0[j] = fmaf(xk, w0[kb + j], a0[j]);
                if (HAS1) a1[j] = fmaf(xk, w1[kb + j], a1[j]);
                a2[j] = fmaf(xk, w2[kb + j], a2[j]);
            }
        }
    }

    float4* o0 = (float4*)(out0 + (size_t)i * H);
#pragma unroll
    for (int j = 0; j < H / 4; j++)
        o0[j] = make_float4(a0[4 * j], a0[4 * j + 1], a0[4 * j + 2], a0[4 * j + 3]);
    if (HAS1) {
        float4* o1 = (float4*)(out1 + (size_t)i * H);
#pragma unroll
        for (int j = 0; j < H / 4; j++)
            o1[j] = make_float4(a1[4 * j], a1[4 * j + 1], a1[4 * j + 2], a1[4 * j + 3]);
    }
    float4* o2 = (float4*)(out2 + (size_t)i * H);
#pragma unroll
    for (int j = 0; j < H / 4; j++)
        o2[j] = make_float4(a2[4 * j], a2[4 * j + 1], a2[4 * j + 2], a2[4 * j + 3]);
}

// ---------------------------------------------------------------------------
// Pull aggregation: h[node] += mean_A(yA[srcs]) (+ mean_B(yB[srcs])).
// 8 threads per node, float4 per thread (8*4 = H floats). rs* are post-bucket
// inclusive-end arrays: row i spans [rs[i-1], rs[i]), rs[-1] := 0.
template <bool HASB>
__global__ __launch_bounds__(256) void pull_kernel(
    const unsigned* __restrict__ rsA, const unsigned* __restrict__ eA, const float* __restrict__ yA,
    const unsigned* __restrict__ rsB, const unsigned* __restrict__ eB, const float* __restrict__ yB,
    float* __restrict__ h, int n)
{
    unsigned t = blockIdx.x * 256u + threadIdx.x;
    unsigned node = t >> 3;
    int j = (int)(t & 7u) * 4;
    if (node >= (unsigned)n) return;

    float4 r = *(const float4*)(h + (size_t)node * H + j);  // root term

    {
        unsigned k0 = node ? rsA[node - 1] : 0u;
        unsigned k1 = rsA[node];
        float4 acc = make_float4(0.f, 0.f, 0.f, 0.f);
        for (unsigned k = k0; k < k1; ++k) {
            unsigned s = eA[k];
            const float4 v = *(const float4*)(yA + (size_t)s * H + j);
            acc.x += v.x; acc.y += v.y; acc.z += v.z; acc.w += v.w;
        }
        unsigned c = k1 - k0;
        float inv = 1.0f / (float)(c > 1u ? c : 1u);
        r.x += acc.x * inv; r.y += acc.y * inv; r.z += acc.z * inv; r.w += acc.w * inv;
    }
    if (HASB) {
        unsigned k0 = node ? rsB[node - 1] : 0u;
        unsigned k1 = rsB[node];
        float4 acc = make_float4(0.f, 0.f, 0.f, 0.f);
        for (unsigned k = k0; k < k1; ++k) {
            unsigned s = eB[k];
            const float4 v = *(const float4*)(yB + (size_t)s * H + j);
            acc.x += v.x; acc.y += v.y; acc.z += v.z; acc.w += v.w;
        }
        unsigned c = k1 - k0;
        float inv = 1.0f / (float)(c > 1u ? c : 1u);
        r.x += acc.x * inv; r.y += acc.y * inv; r.z += acc.z * inv; r.w += acc.w * inv;
    }

    *(float4*)(h + (size_t)node * H + j) = r;
}

// ---------------------------------------------------------------------------
// Head: out = relu(h) @ (lin0_W @ linf_W) + (lin0_b @ linf_W + linf_b).
template <int DOUT>
__global__ __launch_bounds__(256) void final_kernel(
    const float* __restrict__ h, int n,
    const float* __restrict__ lin0W, const float* __restrict__ lin0b,
    const float* __restrict__ linfW, const float* __restrict__ linfb,
    float* __restrict__ out)
{
    __shared__ float we[H * DOUT];
    __shared__ float be[DOUT];
    if (threadIdx.x < H * DOUT) {
        int k = threadIdx.x / DOUT, c = threadIdx.x % DOUT;
        float s = 0.0f;
        for (int m = 0; m < H; m++) s += lin0W[k * H + m] * linfW[m * DOUT + c];
        we[threadIdx.x] = s;
    }
    if (threadIdx.x >= 128 && threadIdx.x < 128 + DOUT) {
        int c = threadIdx.x - 128;
        float s = linfb[c];
        for (int m = 0; m < H; m++) s += lin0b[m] * linfW[m * DOUT + c];
        be[c] = s;
    }
    __syncthreads();

    int i = blockIdx.x * 256 + threadIdx.x;
    if (i >= n) return;

    const float4* hp = (const float4*)(h + (size_t)i * H);
    float acc[DOUT];
#pragma unroll
    for (int c = 0; c < DOUT; c++) acc[c] = be[c];
#pragma unroll
    for (int q = 0; q < H / 4; q++) {
        float4 v = hp[q];
        float vs[4] = {fmaxf(v.x, 0.0f), fmaxf(v.y, 0.0f), fmaxf(v.z, 0.0f), fmaxf(v.w, 0.0f)};
#pragma unroll
        for (int r = 0; r < 4; r++) {
            int k = q * 4 + r;
#pragma unroll
            for (int c = 0; c < DOUT; c++) acc[c] = fmaf(vs[r], we[k * DOUT + c], acc[c]);
        }
    }
    if constexpr (DOUT == 4) {
        *(float4*)(out + (size_t)i * 4) = make_float4(acc[0], acc[1], acc[2], acc[3]);
    } else {
        *(float2*)(out + (size_t)i * 2) = make_float2(acc[0], acc[1]);
    }
}

// ---------------------------------------------------------------------------
extern "C" void kernel_launch(void* const* d_in, const int* in_sizes, int n_in,
                              void* d_out, int out_size, void* d_ws, size_t ws_size,
                              hipStream_t stream) {
    const float* x_bus = (const float*)d_in[0];
    const float* x_gen = (const float*)d_in[1];
    const int* src_bb = (const int*)d_in[2];
    const int* dst_bb = (const int*)d_in[3];
    const int* src_gb = (const int*)d_in[4];
    const int* dst_gb = (const int*)d_in[5];
    const int* src_bg = (const int*)d_in[6];
    const int* dst_bg = (const int*)d_in[7];
    const float* l1_bb_Wl = (const float*)d_in[8];
    const float* l1_bb_bl = (const float*)d_in[9];
    const float* l1_bb_Wr = (const float*)d_in[10];
    const float* l1_gb_Wl = (const float*)d_in[11];
    const float* l1_gb_bl = (const float*)d_in[12];
    const float* l1_gb_Wr = (const float*)d_in[13];
    const float* l1_bg_Wl = (const float*)d_in[14];
    const float* l1_bg_bl = (const float*)d_in[15];
    const float* l1_bg_Wr = (const float*)d_in[16];
    const float* l2_bb_Wl = (const float*)d_in[17];
    const float* l2_bb_bl = (const float*)d_in[18];
    const float* l2_bb_Wr = (const float*)d_in[19];
    const float* l2_gb_Wl = (const float*)d_in[20];
    const float* l2_gb_bl = (const float*)d_in[21];
    const float* l2_gb_Wr = (const float*)d_in[22];
    const float* l2_bg_Wl = (const float*)d_in[23];
    const float* l2_bg_bl = (const float*)d_in[24];
    const float* l2_bg_Wr = (const float*)d_in[25];
    const float* lin0_bus_W = (const float*)d_in[26];
    const float* lin0_bus_b = (const float*)d_in[27];
    const float* linf_bus_W = (const float*)d_in[28];
    const float* linf_bus_b = (const float*)d_in[29];
    const float* lin0_gen_W = (const float*)d_in[30];
    const float* lin0_gen_b = (const float*)d_in[31];
    const float* linf_gen_W = (const float*)d_in[32];
    const float* linf_gen_b = (const float*)d_in[33];

    // Workspace layout (~101 MB).
    char* ws = (char*)d_ws;
    size_t off = 0;
    auto alloc = [&](size_t bytes) {
        char* p = ws + off;
        off += (bytes + 255) & ~(size_t)255;
        return p;
    };
    unsigned* rs_bb = (unsigned*)alloc((size_t)N_BUS * 4);
    unsigned* rs_gb = (unsigned*)alloc((size_t)N_BUS * 4);
    unsigned* rs_bg = (unsigned*)alloc((size_t)N_GEN * 4);
    unsigned* bsum = (unsigned*)alloc(3 * 256 * 4);
    unsigned* e_bb = (unsigned*)alloc((size_t)E_BB * 4);
    unsigned* e_gb = (unsigned*)alloc((size_t)E_GB * 4);
    unsigned* e_bg = (unsigned*)alloc((size_t)E_BG * 4);
    float* y_bb = (float*)alloc((size_t)N_BUS * H * 4);
    float* y_bg = (float*)alloc((size_t)N_BUS * H * 4);
    float* y_gb = (float*)alloc((size_t)N_GEN * H * 4);
    float* h_bus = (float*)alloc((size_t)N_BUS * H * 4);
    float* h_gen = (float*)alloc((size_t)N_GEN * H * 4);

    // ---- Build CSR (once; graph identical for both layers) ----
    auto build_csr = [&](const int* src, const int* dst, int nE, unsigned* rs, int n,
                         unsigned* bs, unsigned* esrc) {
        int nb = (n + 1023) / 1024;
        hipMemsetAsync(rs, 0, (size_t)n * 4, stream);
        count_kernel<<<(nE + 255) / 256, 256, 0, stream>>>(dst, nE, rs);
        scan_local_kernel<<<nb, 256, 0, stream>>>(rs, n, bs);
        scan_bsums_kernel<<<1, 256, 0, stream>>>(bs, nb);
        scan_add_kernel<<<nb, 256, 0, stream>>>(rs, n, bs);
        bucket_kernel<<<(nE + 255) / 256, 256, 0, stream>>>(src, dst, nE, rs, esrc);
    };
    build_csr(src_bb, dst_bb, E_BB, rs_bb, N_BUS, bsum, e_bb);
    build_csr(src_gb, dst_gb, E_GB, rs_gb, N_BUS, bsum + 256, e_gb);
    build_csr(src_bg, dst_bg, E_BG, rs_bg, N_GEN, bsum + 512, e_bg);

    const int gb_bus = (N_BUS + 255) / 256;
    const int gb_gen = (N_GEN + 255) / 256;
    const int gp_bus = (N_BUS * 8 + 255) / 256;
    const int gp_gen = (N_GEN * 8 + 255) / 256;

    // ---- Layer 1 ----
    transform_kernel<64, true, false><<<gb_bus, 256, 0, stream>>>(
        x_bus, N_BUS, l1_bb_Wl, y_bb, l1_bg_Wl, y_bg,
        l1_bb_Wr, l1_gb_Wr, l1_bb_bl, l1_gb_bl, h_bus);
    transform_kernel<64, false, false><<<gb_gen, 256, 0, stream>>>(
        x_gen, N_GEN, l1_gb_Wl, y_gb, nullptr, nullptr,
        l1_bg_Wr, nullptr, l1_bg_bl, nullptr, h_gen);
    pull_kernel<true><<<gp_bus, 256, 0, stream>>>(rs_bb, e_bb, y_bb, rs_gb, e_gb, y_gb, h_bus, N_BUS);
    pull_kernel<false><<<gp_gen, 256, 0, stream>>>(rs_bg, e_bg, y_bg, nullptr, nullptr, nullptr, h_gen, N_GEN);

    // ---- Layer 2 (relu on load; root written in-place over h_*) ----
    transform_kernel<32, true, true><<<gb_bus, 256, 0, stream>>>(
        h_bus, N_BUS, l2_bb_Wl, y_bb, l2_bg_Wl, y_bg,
        l2_bb_Wr, l2_gb_Wr, l2_bb_bl, l2_gb_bl, h_bus);
    transform_kernel<32, false, true><<<gb_gen, 256, 0, stream>>>(
        h_gen, N_GEN, l2_gb_Wl, y_gb, nullptr, nullptr,
        l2_bg_Wr, nullptr, l2_bg_bl, nullptr, h_gen);
    pull_kernel<true><<<gp_bus, 256, 0, stream>>>(rs_bb, e_bb, y_bb, rs_gb, e_gb, y_gb, h_bus, N_BUS);
    pull_kernel<false><<<gp_gen, 256, 0, stream>>>(rs_bg, e_bg, y_bg, nullptr, nullptr, nullptr, h_gen, N_GEN);

    // ---- Head ----
    final_kernel<4><<<gb_bus, 256, 0, stream>>>(h_bus, N_BUS, lin0_bus_W, lin0_bus_b,
                                                linf_bus_W, linf_bus_b, (float*)d_out);
    final_kernel<2><<<gb_gen, 256, 0, stream>>>(h_gen, N_GEN, lin0_gen_W, lin0_gen_b,
                                                linf_gen_W, linf_gen_b, (float*)d_out + (size_t)N_BUS * 4);
}

// Round 3
// 608.837 us; speedup vs baseline: 3.9856x; 1.3018x over previous
//
#include <hip/hip_runtime.h>

#define N_BUS 200000
#define N_GEN 50000
#define E_BB 1600000
#define E_GB 400000
#define E_BG 400000
#define H 32
#define NBINS 1024   // max coarse buckets (>= ceil(200000/256) = 782)
#define EPT 16       // edges per thread in partition (chunk = 4096)

// ---------------------------------------------------------------------------
// Coarse histogram over 256-dst buckets, LDS-privatized.
__global__ __launch_bounds__(256) void coarse_hist_kernel(const int* __restrict__ dst,
                                                          int nE, unsigned* __restrict__ bcnt) {
    __shared__ unsigned h[NBINS];
    for (int i = threadIdx.x; i < NBINS; i += 256) h[i] = 0;
    __syncthreads();
    for (int e = blockIdx.x * 256 + threadIdx.x; e < nE; e += gridDim.x * 256)
        atomicAdd(&h[(unsigned)dst[e] >> 8], 1u);
    __syncthreads();
    for (int i = threadIdx.x; i < NBINS; i += 256)
        if (h[i]) atomicAdd(&bcnt[i], h[i]);
}

// In-place exclusive scan of exactly 1024 entries, single block (256 thr x 4).
__global__ __launch_bounds__(256) void scan1024_kernel(unsigned* __restrict__ a) {
    __shared__ unsigned sh[256];
    int tid = threadIdx.x;
    int base = tid * 4;
    unsigned v[4], ts = 0;
#pragma unroll
    for (int q = 0; q < 4; q++) { v[q] = a[base + q]; ts += v[q]; }
    sh[tid] = ts;
    __syncthreads();
#pragma unroll
    for (int d = 1; d < 256; d <<= 1) {
        unsigned t = (tid >= d) ? sh[tid - d] : 0u;
        __syncthreads();
        sh[tid] += t;
        __syncthreads();
    }
    unsigned run = sh[tid] - ts;
#pragma unroll
    for (int q = 0; q < 4; q++) { a[base + q] = run; run += v[q]; }
}

// Partition scatter: each block stages a 4096-edge chunk, reserves per-bucket
// runs with ONE global atomic per (block,bucket), writes packed (dstl<<24|src)
// into block-private runs (same-block line ownership -> low write amp).
__global__ __launch_bounds__(256) void partition_kernel(const int* __restrict__ src,
                                                        const int* __restrict__ dst, int nE,
                                                        unsigned* __restrict__ cursor,
                                                        unsigned* __restrict__ pairs) {
    __shared__ unsigned hist[NBINS];
    __shared__ unsigned base[NBINS];
    const int tid = threadIdx.x;
    const int cbase = blockIdx.x * (256 * EPT);

    unsigned es[EPT], ed[EPT];
#pragma unroll
    for (int q = 0; q < EPT; q++) {
        int i = cbase + q * 256 + tid;
        if (i < nE) { es[q] = (unsigned)src[i]; ed[q] = (unsigned)dst[i]; }
        else ed[q] = 0xFFFFFFFFu;
    }
    for (int i = tid; i < NBINS; i += 256) hist[i] = 0;
    __syncthreads();
#pragma unroll
    for (int q = 0; q < EPT; q++)
        if (ed[q] != 0xFFFFFFFFu) atomicAdd(&hist[ed[q] >> 8], 1u);
    __syncthreads();
    for (int i = tid; i < NBINS; i += 256) {
        unsigned c = hist[i];
        base[i] = c ? atomicAdd(&cursor[i], c) : 0u;
        hist[i] = 0;  // reuse as local cursor
    }
    __syncthreads();
#pragma unroll
    for (int q = 0; q < EPT; q++) {
        if (ed[q] != 0xFFFFFFFFu) {
            unsigned b = ed[q] >> 8;
            unsigned off = atomicAdd(&hist[b], 1u);
            pairs[base[b] + off] = ((ed[q] & 255u) << 24) | es[q];
        }
    }
}

// Fine CSR: one block per coarse bucket. Builds per-dst row ends (rs) and
// dst-sorted src lists (esrc) within the bucket's contiguous region.
__global__ __launch_bounds__(256) void fine_csr_kernel(const unsigned* __restrict__ cursor,
                                                       const unsigned* __restrict__ pairs,
                                                       unsigned* __restrict__ rs,
                                                       unsigned* __restrict__ esrc, int nDst) {
    __shared__ unsigned cnt[256];
    __shared__ unsigned sh[256];
    const int tid = threadIdx.x;
    const int b = blockIdx.x;
    const unsigned start = b ? cursor[b - 1] : 0u;
    const unsigned end = cursor[b];

    cnt[tid] = 0;
    __syncthreads();
    for (unsigned k = start + tid; k < end; k += 256)
        atomicAdd(&cnt[pairs[k] >> 24], 1u);
    __syncthreads();
    unsigned c = cnt[tid];
    sh[tid] = c;
    __syncthreads();
#pragma unroll
    for (int d = 1; d < 256; d <<= 1) {
        unsigned t = (tid >= d) ? sh[tid - d] : 0u;
        __syncthreads();
        sh[tid] += t;
        __syncthreads();
    }
    int gd = b * 256 + tid;
    if (gd < nDst) rs[gd] = start + sh[tid];  // inclusive row end
    cnt[tid] = sh[tid] - c;                   // exclusive offset -> cursor
    __syncthreads();
    for (unsigned k = start + tid; k < end; k += 256) {
        unsigned p = pairs[k];
        unsigned off = atomicAdd(&cnt[p >> 24], 1u);
        esrc[start + off] = p & 0x00FFFFFFu;
    }
}

// ---------------------------------------------------------------------------
// Fused node transform: y0 = x@W0, y1 = x@W1 (opt), h = x@(W2a+W2b)+(ba+bb).
template <int DIN, bool HAS1, bool RELU_IN>
__global__ __launch_bounds__(256) void transform_kernel(
    const float* x, int n,
    const float* __restrict__ W0, float* __restrict__ out0,
    const float* __restrict__ W1, float* __restrict__ out1,
    const float* __restrict__ W2a, const float* __restrict__ W2b,
    const float* __restrict__ ba, const float* __restrict__ bb,
    float* out2)
{
    __shared__ float w0[DIN * H];
    __shared__ float w1[HAS1 ? DIN * H : 1];
    __shared__ float w2[DIN * H];
    __shared__ float bias[H];

    for (int idx = threadIdx.x; idx < DIN * H; idx += 256) {
        w0[idx] = W0[idx];
        if (HAS1) w1[idx] = W1[idx];
        w2[idx] = W2a[idx] + (W2b ? W2b[idx] : 0.0f);
    }
    if (threadIdx.x < H)
        bias[threadIdx.x] = ba[threadIdx.x] + (bb ? bb[threadIdx.x] : 0.0f);
    __syncthreads();

    int i = blockIdx.x * 256 + threadIdx.x;
    if (i >= n) return;

    const float4* xp = (const float4*)(x + (size_t)i * DIN);

    float a0[H], a1[HAS1 ? H : 1], a2[H];
#pragma unroll
    for (int j = 0; j < H; j++) {
        a0[j] = 0.0f;
        if (HAS1) a1[j] = 0.0f;
        a2[j] = bias[j];
    }

    for (int kk = 0; kk < DIN / 4; ++kk) {
        float4 xv = xp[kk];
        float xs[4] = {xv.x, xv.y, xv.z, xv.w};
#pragma unroll
        for (int q = 0; q < 4; q++) {
            float xk = RELU_IN ? fmaxf(xs[q], 0.0f) : xs[q];
            const int kb = (kk * 4 + q) * H;
#pragma unroll
            for (int j = 0; j < H; j++) {
                a0[j] = fmaf(xk, w0[kb + j], a0[j]);
                if (HAS1) a1[j] = fmaf(xk, w1[kb + j], a1[j]);
                a2[j] = fmaf(xk, w2[kb + j], a2[j]);
            }
        }
    }

    float4* o0 = (float4*)(out0 + (size_t)i * H);
#pragma unroll
    for (int j = 0; j < H / 4; j++)
        o0[j] = make_float4(a0[4 * j], a0[4 * j + 1], a0[4 * j + 2], a0[4 * j + 3]);
    if (HAS1) {
        float4* o1 = (float4*)(out1 + (size_t)i * H);
#pragma unroll
        for (int j = 0; j < H / 4; j++)
            o1[j] = make_float4(a1[4 * j], a1[4 * j + 1], a1[4 * j + 2], a1[4 * j + 3]);
    }
    float4* o2 = (float4*)(out2 + (size_t)i * H);
#pragma unroll
    for (int j = 0; j < H / 4; j++)
        o2[j] = make_float4(a2[4 * j], a2[4 * j + 1], a2[4 * j + 2], a2[4 * j + 3]);
}

// ---------------------------------------------------------------------------
// Pull aggregation: h[node] += mean_A(yA[srcs]) (+ mean_B(yB[srcs])).
// 8 threads per node, float4 per thread. rs row i spans [rs[i-1], rs[i]).
template <bool HASB>
__global__ __launch_bounds__(256) void pull_kernel(
    const unsigned* __restrict__ rsA, const unsigned* __restrict__ eA, const float* __restrict__ yA,
    const unsigned* __restrict__ rsB, const unsigned* __restrict__ eB, const float* __restrict__ yB,
    float* __restrict__ h, int n)
{
    unsigned t = blockIdx.x * 256u + threadIdx.x;
    unsigned node = t >> 3;
    int j = (int)(t & 7u) * 4;
    if (node >= (unsigned)n) return;

    float4 r = *(const float4*)(h + (size_t)node * H + j);  // root term

    {
        unsigned k0 = node ? rsA[node - 1] : 0u;
        unsigned k1 = rsA[node];
        float4 acc = make_float4(0.f, 0.f, 0.f, 0.f);
        for (unsigned k = k0; k < k1; ++k) {
            unsigned s = eA[k];
            const float4 v = *(const float4*)(yA + (size_t)s * H + j);
            acc.x += v.x; acc.y += v.y; acc.z += v.z; acc.w += v.w;
        }
        unsigned c = k1 - k0;
        float inv = 1.0f / (float)(c > 1u ? c : 1u);
        r.x += acc.x * inv; r.y += acc.y * inv; r.z += acc.z * inv; r.w += acc.w * inv;
    }
    if (HASB) {
        unsigned k0 = node ? rsB[node - 1] : 0u;
        unsigned k1 = rsB[node];
        float4 acc = make_float4(0.f, 0.f, 0.f, 0.f);
        for (unsigned k = k0; k < k1; ++k) {
            unsigned s = eB[k];
            const float4 v = *(const float4*)(yB + (size_t)s * H + j);
            acc.x += v.x; acc.y += v.y; acc.z += v.z; acc.w += v.w;
        }
        unsigned c = k1 - k0;
        float inv = 1.0f / (float)(c > 1u ? c : 1u);
        r.x += acc.x * inv; r.y += acc.y * inv; r.z += acc.z * inv; r.w += acc.w * inv;
    }

    *(float4*)(h + (size_t)node * H + j) = r;
}

// ---------------------------------------------------------------------------
// Head: out = relu(h) @ (lin0_W @ linf_W) + (lin0_b @ linf_W + linf_b).
template <int DOUT>
__global__ __launch_bounds__(256) void final_kernel(
    const float* __restrict__ h, int n,
    const float* __restrict__ lin0W, const float* __restrict__ lin0b,
    const float* __restrict__ linfW, const float* __restrict__ linfb,
    float* __restrict__ out)
{
    __shared__ float we[H * DOUT];
    __shared__ float be[DOUT];
    if (threadIdx.x < H * DOUT) {
        int k = threadIdx.x / DOUT, c = threadIdx.x % DOUT;
        float s = 0.0f;
        for (int m = 0; m < H; m++) s += lin0W[k * H + m] * linfW[m * DOUT + c];
        we[threadIdx.x] = s;
    }
    if (threadIdx.x >= 128 && threadIdx.x < 128 + DOUT) {
        int c = threadIdx.x - 128;
        float s = linfb[c];
        for (int m = 0; m < H; m++) s += lin0b[m] * linfW[m * DOUT + c];
        be[c] = s;
    }
    __syncthreads();

    int i = blockIdx.x * 256 + threadIdx.x;
    if (i >= n) return;

    const float4* hp = (const float4*)(h + (size_t)i * H);
    float acc[DOUT];
#pragma unroll
    for (int c = 0; c < DOUT; c++) acc[c] = be[c];
#pragma unroll
    for (int q = 0; q < H / 4; q++) {
        float4 v = hp[q];
        float vs[4] = {fmaxf(v.x, 0.0f), fmaxf(v.y, 0.0f), fmaxf(v.z, 0.0f), fmaxf(v.w, 0.0f)};
#pragma unroll
        for (int r = 0; r < 4; r++) {
            int k = q * 4 + r;
#pragma unroll
            for (int c = 0; c < DOUT; c++) acc[c] = fmaf(vs[r], we[k * DOUT + c], acc[c]);
        }
    }
    if constexpr (DOUT == 4) {
        *(float4*)(out + (size_t)i * 4) = make_float4(acc[0], acc[1], acc[2], acc[3]);
    } else {
        *(float2*)(out + (size_t)i * 2) = make_float2(acc[0], acc[1]);
    }
}

// ---------------------------------------------------------------------------
extern "C" void kernel_launch(void* const* d_in, const int* in_sizes, int n_in,
                              void* d_out, int out_size, void* d_ws, size_t ws_size,
                              hipStream_t stream) {
    const float* x_bus = (const float*)d_in[0];
    const float* x_gen = (const float*)d_in[1];
    const int* src_bb = (const int*)d_in[2];
    const int* dst_bb = (const int*)d_in[3];
    const int* src_gb = (const int*)d_in[4];
    const int* dst_gb = (const int*)d_in[5];
    const int* src_bg = (const int*)d_in[6];
    const int* dst_bg = (const int*)d_in[7];
    const float* l1_bb_Wl = (const float*)d_in[8];
    const float* l1_bb_bl = (const float*)d_in[9];
    const float* l1_bb_Wr = (const float*)d_in[10];
    const float* l1_gb_Wl = (const float*)d_in[11];
    const float* l1_gb_bl = (const float*)d_in[12];
    const float* l1_gb_Wr = (const float*)d_in[13];
    const float* l1_bg_Wl = (const float*)d_in[14];
    const float* l1_bg_bl = (const float*)d_in[15];
    const float* l1_bg_Wr = (const float*)d_in[16];
    const float* l2_bb_Wl = (const float*)d_in[17];
    const float* l2_bb_bl = (const float*)d_in[18];
    const float* l2_bb_Wr = (const float*)d_in[19];
    const float* l2_gb_Wl = (const float*)d_in[20];
    const float* l2_gb_bl = (const float*)d_in[21];
    const float* l2_gb_Wr = (const float*)d_in[22];
    const float* l2_bg_Wl = (const float*)d_in[23];
    const float* l2_bg_bl = (const float*)d_in[24];
    const float* l2_bg_Wr = (const float*)d_in[25];
    const float* lin0_bus_W = (const float*)d_in[26];
    const float* lin0_bus_b = (const float*)d_in[27];
    const float* linf_bus_W = (const float*)d_in[28];
    const float* linf_bus_b = (const float*)d_in[29];
    const float* lin0_gen_W = (const float*)d_in[30];
    const float* lin0_gen_b = (const float*)d_in[31];
    const float* linf_gen_W = (const float*)d_in[32];
    const float* linf_gen_b = (const float*)d_in[33];

    // Workspace layout (~101 MB).
    char* ws = (char*)d_ws;
    size_t off = 0;
    auto alloc = [&](size_t bytes) {
        char* p = ws + off;
        off += (bytes + 255) & ~(size_t)255;
        return p;
    };
    unsigned* rs_bb = (unsigned*)alloc((size_t)N_BUS * 4);
    unsigned* rs_gb = (unsigned*)alloc((size_t)N_BUS * 4);
    unsigned* rs_bg = (unsigned*)alloc((size_t)N_GEN * 4);
    unsigned* cur_bb = (unsigned*)alloc(NBINS * 4);
    unsigned* cur_gb = (unsigned*)alloc(NBINS * 4);
    unsigned* cur_bg = (unsigned*)alloc(NBINS * 4);
    unsigned* e_bb = (unsigned*)alloc((size_t)E_BB * 4);
    unsigned* e_gb = (unsigned*)alloc((size_t)E_GB * 4);
    unsigned* e_bg = (unsigned*)alloc((size_t)E_BG * 4);
    float* y_bb = (float*)alloc((size_t)N_BUS * H * 4);
    float* y_bg = (float*)alloc((size_t)N_BUS * H * 4);
    float* y_gb = (float*)alloc((size_t)N_GEN * H * 4);
    float* h_bus = (float*)alloc((size_t)N_BUS * H * 4);
    float* h_gen = (float*)alloc((size_t)N_GEN * H * 4);

    // Pair buffers alias y_* (CSR build completes before transforms write y).
    unsigned* p_bb = (unsigned*)y_bb;  // 6.4 MB <= 25.6 MB
    unsigned* p_gb = (unsigned*)y_bg;  // 1.6 MB
    unsigned* p_bg = (unsigned*)y_gb;  // 1.6 MB

    // cursors are contiguous: one memset.
    hipMemsetAsync(cur_bb, 0, 3 * NBINS * 4, stream);

    auto build_csr = [&](const int* src, const int* dst, int nE, int nDst,
                         unsigned* cur, unsigned* pairs, unsigned* rs, unsigned* esrc) {
        int hb = (nE + 255) / 256; if (hb > 256) hb = 256;
        coarse_hist_kernel<<<hb, 256, 0, stream>>>(dst, nE, cur);
        scan1024_kernel<<<1, 256, 0, stream>>>(cur);
        partition_kernel<<<(nE + 256 * EPT - 1) / (256 * EPT), 256, 0, stream>>>(src, dst, nE, cur, pairs);
        fine_csr_kernel<<<(nDst + 255) / 256, 256, 0, stream>>>(cur, pairs, rs, esrc, nDst);
    };
    build_csr(src_bb, dst_bb, E_BB, N_BUS, cur_bb, p_bb, rs_bb, e_bb);
    build_csr(src_gb, dst_gb, E_GB, N_BUS, cur_gb, p_gb, rs_gb, e_gb);
    build_csr(src_bg, dst_bg, E_BG, N_GEN, cur_bg, p_bg, rs_bg, e_bg);

    const int gb_bus = (N_BUS + 255) / 256;
    const int gb_gen = (N_GEN + 255) / 256;
    const int gp_bus = (N_BUS * 8 + 255) / 256;
    const int gp_gen = (N_GEN * 8 + 255) / 256;

    // ---- Layer 1 ----
    transform_kernel<64, true, false><<<gb_bus, 256, 0, stream>>>(
        x_bus, N_BUS, l1_bb_Wl, y_bb, l1_bg_Wl, y_bg,
        l1_bb_Wr, l1_gb_Wr, l1_bb_bl, l1_gb_bl, h_bus);
    transform_kernel<64, false, false><<<gb_gen, 256, 0, stream>>>(
        x_gen, N_GEN, l1_gb_Wl, y_gb, nullptr, nullptr,
        l1_bg_Wr, nullptr, l1_bg_bl, nullptr, h_gen);
    pull_kernel<true><<<gp_bus, 256, 0, stream>>>(rs_bb, e_bb, y_bb, rs_gb, e_gb, y_gb, h_bus, N_BUS);
    pull_kernel<false><<<gp_gen, 256, 0, stream>>>(rs_bg, e_bg, y_bg, nullptr, nullptr, nullptr, h_gen, N_GEN);

    // ---- Layer 2 (relu on load; root written in-place over h_*) ----
    transform_kernel<32, true, true><<<gb_bus, 256, 0, stream>>>(
        h_bus, N_BUS, l2_bb_Wl, y_bb, l2_bg_Wl, y_bg,
        l2_bb_Wr, l2_gb_Wr, l2_bb_bl, l2_gb_bl, h_bus);
    transform_kernel<32, false, true><<<gb_gen, 256, 0, stream>>>(
        h_gen, N_GEN, l2_gb_Wl, y_gb, nullptr, nullptr,
        l2_bg_Wr, nullptr, l2_bg_bl, nullptr, h_gen);
    pull_kernel<true><<<gp_bus, 256, 0, stream>>>(rs_bb, e_bb, y_bb, rs_gb, e_gb, y_gb, h_bus, N_BUS);
    pull_kernel<false><<<gp_gen, 256, 0, stream>>>(rs_bg, e_bg, y_bg, nullptr, nullptr, nullptr, h_gen, N_GEN);

    // ---- Head ----
    final_kernel<4><<<gb_bus, 256, 0, stream>>>(h_bus, N_BUS, lin0_bus_W, lin0_bus_b,
                                                linf_bus_W, linf_bus_b, (float*)d_out);
    final_kernel<2><<<gb_gen, 256, 0, stream>>>(h_gen, N_GEN, lin0_gen_W, lin0_gen_b,
                                                linf_gen_W, linf_gen_b, (float*)d_out + (size_t)N_BUS * 4);
}

// Round 4
// 564.492 us; speedup vs baseline: 4.2987x; 1.0786x over previous
//
#include <hip/hip_runtime.h>

#define N_BUS 200000
#define N_GEN 50000
#define E_BB 1600000
#define E_GB 400000
#define E_BG 400000
#define H 32
#define NBINS 1024   // max coarse buckets (>= ceil(200000/256) = 782)
#define EPT 16       // edges per thread in partition (chunk = 4096)

// ---------------------------------------------------------------------------
// Coarse histogram over 256-dst buckets, LDS-privatized.
__global__ __launch_bounds__(256) void coarse_hist_kernel(const int* __restrict__ dst,
                                                          int nE, unsigned* __restrict__ bcnt) {
    __shared__ unsigned h[NBINS];
    for (int i = threadIdx.x; i < NBINS; i += 256) h[i] = 0;
    __syncthreads();
    for (int e = blockIdx.x * 256 + threadIdx.x; e < nE; e += gridDim.x * 256)
        atomicAdd(&h[(unsigned)dst[e] >> 8], 1u);
    __syncthreads();
    for (int i = threadIdx.x; i < NBINS; i += 256)
        if (h[i]) atomicAdd(&bcnt[i], h[i]);
}

// In-place exclusive scan of exactly 1024 entries, single block (256 thr x 4).
__global__ __launch_bounds__(256) void scan1024_kernel(unsigned* __restrict__ a) {
    __shared__ unsigned sh[256];
    int tid = threadIdx.x;
    int base = tid * 4;
    unsigned v[4], ts = 0;
#pragma unroll
    for (int q = 0; q < 4; q++) { v[q] = a[base + q]; ts += v[q]; }
    sh[tid] = ts;
    __syncthreads();
#pragma unroll
    for (int d = 1; d < 256; d <<= 1) {
        unsigned t = (tid >= d) ? sh[tid - d] : 0u;
        __syncthreads();
        sh[tid] += t;
        __syncthreads();
    }
    unsigned run = sh[tid] - ts;
#pragma unroll
    for (int q = 0; q < 4; q++) { a[base + q] = run; run += v[q]; }
}

// Partition scatter: each block stages a 4096-edge chunk, reserves per-bucket
// runs with ONE global atomic per (block,bucket), writes packed (dstl<<24|src)
// into block-private runs (same-block line ownership -> low write amp).
__global__ __launch_bounds__(256) void partition_kernel(const int* __restrict__ src,
                                                        const int* __restrict__ dst, int nE,
                                                        unsigned* __restrict__ cursor,
                                                        unsigned* __restrict__ pairs) {
    __shared__ unsigned hist[NBINS];
    __shared__ unsigned base[NBINS];
    const int tid = threadIdx.x;
    const int cbase = blockIdx.x * (256 * EPT);

    unsigned es[EPT], ed[EPT];
#pragma unroll
    for (int q = 0; q < EPT; q++) {
        int i = cbase + q * 256 + tid;
        if (i < nE) { es[q] = (unsigned)src[i]; ed[q] = (unsigned)dst[i]; }
        else ed[q] = 0xFFFFFFFFu;
    }
    for (int i = tid; i < NBINS; i += 256) hist[i] = 0;
    __syncthreads();
#pragma unroll
    for (int q = 0; q < EPT; q++)
        if (ed[q] != 0xFFFFFFFFu) atomicAdd(&hist[ed[q] >> 8], 1u);
    __syncthreads();
    for (int i = tid; i < NBINS; i += 256) {
        unsigned c = hist[i];
        base[i] = c ? atomicAdd(&cursor[i], c) : 0u;
        hist[i] = 0;  // reuse as local cursor
    }
    __syncthreads();
#pragma unroll
    for (int q = 0; q < EPT; q++) {
        if (ed[q] != 0xFFFFFFFFu) {
            unsigned b = ed[q] >> 8;
            unsigned off = atomicAdd(&hist[b], 1u);
            pairs[base[b] + off] = ((ed[q] & 255u) << 24) | es[q];
        }
    }
}

// Fine CSR: one block per coarse bucket. Builds per-dst row ends (rs) and
// dst-sorted src lists (esrc) within the bucket's contiguous region.
__global__ __launch_bounds__(256) void fine_csr_kernel(const unsigned* __restrict__ cursor,
                                                       const unsigned* __restrict__ pairs,
                                                       unsigned* __restrict__ rs,
                                                       unsigned* __restrict__ esrc, int nDst) {
    __shared__ unsigned cnt[256];
    __shared__ unsigned sh[256];
    const int tid = threadIdx.x;
    const int b = blockIdx.x;
    const unsigned start = b ? cursor[b - 1] : 0u;
    const unsigned end = cursor[b];

    cnt[tid] = 0;
    __syncthreads();
    for (unsigned k = start + tid; k < end; k += 256)
        atomicAdd(&cnt[pairs[k] >> 24], 1u);
    __syncthreads();
    unsigned c = cnt[tid];
    sh[tid] = c;
    __syncthreads();
#pragma unroll
    for (int d = 1; d < 256; d <<= 1) {
        unsigned t = (tid >= d) ? sh[tid - d] : 0u;
        __syncthreads();
        sh[tid] += t;
        __syncthreads();
    }
    int gd = b * 256 + tid;
    if (gd < nDst) rs[gd] = start + sh[tid];  // inclusive row end
    cnt[tid] = sh[tid] - c;                   // exclusive offset -> cursor
    __syncthreads();
    for (unsigned k = start + tid; k < end; k += 256) {
        unsigned p = pairs[k];
        unsigned off = atomicAdd(&cnt[p >> 24], 1u);
        esrc[start + off] = p & 0x00FFFFFFu;
    }
}

// ---------------------------------------------------------------------------
// Prep: concatenate weights into k-major Wcat[K][NOUT] per transform, fold
// Wr sums and biases. Bus (NOUT=96): [Wl_bb | Wl_bg | Wr_bb+Wr_gb];
// gen (NOUT=64): [Wl_gb | Wr_bg]. Bias vectors aligned to cols (0 for y cols).
__global__ __launch_bounds__(256) void prep_kernel(
    const float* __restrict__ l1_bb_Wl, const float* __restrict__ l1_bb_bl, const float* __restrict__ l1_bb_Wr,
    const float* __restrict__ l1_gb_Wl, const float* __restrict__ l1_gb_bl, const float* __restrict__ l1_gb_Wr,
    const float* __restrict__ l1_bg_Wl, const float* __restrict__ l1_bg_bl, const float* __restrict__ l1_bg_Wr,
    const float* __restrict__ l2_bb_Wl, const float* __restrict__ l2_bb_bl, const float* __restrict__ l2_bb_Wr,
    const float* __restrict__ l2_gb_Wl, const float* __restrict__ l2_gb_bl, const float* __restrict__ l2_gb_Wr,
    const float* __restrict__ l2_bg_Wl, const float* __restrict__ l2_bg_bl, const float* __restrict__ l2_bg_Wr,
    float* __restrict__ W1b, float* __restrict__ B1b,
    float* __restrict__ W1g, float* __restrict__ B1g,
    float* __restrict__ W2b, float* __restrict__ B2b,
    float* __restrict__ W2g, float* __restrict__ B2g)
{
    int t = blockIdx.x * 256 + threadIdx.x;
    int NT = gridDim.x * 256;
    for (int idx = t; idx < 64 * 32; idx += NT) {
        int k = idx >> 5, j = idx & 31;
        W1b[k * 96 + j]      = l1_bb_Wl[idx];
        W1b[k * 96 + 32 + j] = l1_bg_Wl[idx];
        W1b[k * 96 + 64 + j] = l1_bb_Wr[idx] + l1_gb_Wr[idx];
        W1g[k * 64 + j]      = l1_gb_Wl[idx];
        W1g[k * 64 + 32 + j] = l1_bg_Wr[idx];
    }
    for (int idx = t; idx < 32 * 32; idx += NT) {
        int k = idx >> 5, j = idx & 31;
        W2b[k * 96 + j]      = l2_bb_Wl[idx];
        W2b[k * 96 + 32 + j] = l2_bg_Wl[idx];
        W2b[k * 96 + 64 + j] = l2_bb_Wr[idx] + l2_gb_Wr[idx];
        W2g[k * 64 + j]      = l2_gb_Wl[idx];
        W2g[k * 64 + 32 + j] = l2_bg_Wr[idx];
    }
    if (t < 96) {
        B1b[t] = (t < 64) ? 0.0f : l1_bb_bl[t - 64] + l1_gb_bl[t - 64];
        B2b[t] = (t < 64) ? 0.0f : l2_bb_bl[t - 64] + l2_gb_bl[t - 64];
    }
    if (t < 64) {
        B1g[t] = (t < 32) ? 0.0f : l1_bg_bl[t - 32];
        B2g[t] = (t < 32) ? 0.0f : l2_bg_bl[t - 32];
    }
}

// ---------------------------------------------------------------------------
// Node transform v2: thread = node, acc[NOUT] in VGPRs, weights read via
// wave-uniform (scalar) loads -- no LDS, no syncthreads. Output chunk c of 32
// cols goes to oc (chunk layout: NOUT=96 -> o0,o1,o2; NOUT=64 -> o0,o2).
// x may alias o2 (in-place root write): per-thread row ownership, no hazard.
template <int K, int NOUT, bool RELU_IN>
__global__ __launch_bounds__(256, 3) void transform2_kernel(
    const float* x, int n,
    const float* __restrict__ Wcat, const float* __restrict__ bias,
    float* __restrict__ o0, float* __restrict__ o1, float* o2)
{
    int i = blockIdx.x * 256 + threadIdx.x;
    if (i >= n) return;

    float acc[NOUT];
#pragma unroll
    for (int j = 0; j < NOUT; j++) acc[j] = bias[j];

    const float4* xp = (const float4*)(x + (size_t)i * K);
    for (int kk = 0; kk < K / 4; ++kk) {
        float4 xv = xp[kk];
        float xs[4] = {xv.x, xv.y, xv.z, xv.w};
#pragma unroll
        for (int q = 0; q < 4; q++) {
            float xk = RELU_IN ? fmaxf(xs[q], 0.0f) : xs[q];
            const float* __restrict__ wr = Wcat + (kk * 4 + q) * NOUT;
#pragma unroll
            for (int j = 0; j < NOUT; j++) acc[j] = fmaf(xk, wr[j], acc[j]);
        }
    }

    float* outs[3];
    outs[0] = o0;
    if (NOUT == 96) { outs[1] = o1; outs[2] = o2; }
    else { outs[1] = o2; outs[2] = nullptr; }
#pragma unroll
    for (int c = 0; c < NOUT / 32; c++) {
        float4* p = (float4*)(outs[c] + (size_t)i * 32);
#pragma unroll
        for (int j = 0; j < 8; j++)
            p[j] = make_float4(acc[c * 32 + 4 * j], acc[c * 32 + 4 * j + 1],
                               acc[c * 32 + 4 * j + 2], acc[c * 32 + 4 * j + 3]);
    }
}

// ---------------------------------------------------------------------------
// Pull aggregation: h[node] += mean_A(yA[srcs]) (+ mean_B(yB[srcs])).
// 8 threads per node, float4 per thread. rs row i spans [rs[i-1], rs[i]).
template <bool HASB>
__global__ __launch_bounds__(256) void pull_kernel(
    const unsigned* __restrict__ rsA, const unsigned* __restrict__ eA, const float* __restrict__ yA,
    const unsigned* __restrict__ rsB, const unsigned* __restrict__ eB, const float* __restrict__ yB,
    float* __restrict__ h, int n)
{
    unsigned t = blockIdx.x * 256u + threadIdx.x;
    unsigned node = t >> 3;
    int j = (int)(t & 7u) * 4;
    if (node >= (unsigned)n) return;

    float4 r = *(const float4*)(h + (size_t)node * H + j);  // root term

    {
        unsigned k0 = node ? rsA[node - 1] : 0u;
        unsigned k1 = rsA[node];
        float4 acc = make_float4(0.f, 0.f, 0.f, 0.f);
        for (unsigned k = k0; k < k1; ++k) {
            unsigned s = eA[k];
            const float4 v = *(const float4*)(yA + (size_t)s * H + j);
            acc.x += v.x; acc.y += v.y; acc.z += v.z; acc.w += v.w;
        }
        unsigned c = k1 - k0;
        float inv = 1.0f / (float)(c > 1u ? c : 1u);
        r.x += acc.x * inv; r.y += acc.y * inv; r.z += acc.z * inv; r.w += acc.w * inv;
    }
    if (HASB) {
        unsigned k0 = node ? rsB[node - 1] : 0u;
        unsigned k1 = rsB[node];
        float4 acc = make_float4(0.f, 0.f, 0.f, 0.f);
        for (unsigned k = k0; k < k1; ++k) {
            unsigned s = eB[k];
            const float4 v = *(const float4*)(yB + (size_t)s * H + j);
            acc.x += v.x; acc.y += v.y; acc.z += v.z; acc.w += v.w;
        }
        unsigned c = k1 - k0;
        float inv = 1.0f / (float)(c > 1u ? c : 1u);
        r.x += acc.x * inv; r.y += acc.y * inv; r.z += acc.z * inv; r.w += acc.w * inv;
    }

    *(float4*)(h + (size_t)node * H + j) = r;
}

// ---------------------------------------------------------------------------
// Head: out = relu(h) @ (lin0_W @ linf_W) + (lin0_b @ linf_W + linf_b).
template <int DOUT>
__global__ __launch_bounds__(256) void final_kernel(
    const float* __restrict__ h, int n,
    const float* __restrict__ lin0W, const float* __restrict__ lin0b,
    const float* __restrict__ linfW, const float* __restrict__ linfb,
    float* __restrict__ out)
{
    __shared__ float we[H * DOUT];
    __shared__ float be[DOUT];
    if (threadIdx.x < H * DOUT) {
        int k = threadIdx.x / DOUT, c = threadIdx.x % DOUT;
        float s = 0.0f;
        for (int m = 0; m < H; m++) s += lin0W[k * H + m] * linfW[m * DOUT + c];
        we[threadIdx.x] = s;
    }
    if (threadIdx.x >= 128 && threadIdx.x < 128 + DOUT) {
        int c = threadIdx.x - 128;
        float s = linfb[c];
        for (int m = 0; m < H; m++) s += lin0b[m] * linfW[m * DOUT + c];
        be[c] = s;
    }
    __syncthreads();

    int i = blockIdx.x * 256 + threadIdx.x;
    if (i >= n) return;

    const float4* hp = (const float4*)(h + (size_t)i * H);
    float acc[DOUT];
#pragma unroll
    for (int c = 0; c < DOUT; c++) acc[c] = be[c];
#pragma unroll
    for (int q = 0; q < H / 4; q++) {
        float4 v = hp[q];
        float vs[4] = {fmaxf(v.x, 0.0f), fmaxf(v.y, 0.0f), fmaxf(v.z, 0.0f), fmaxf(v.w, 0.0f)};
#pragma unroll
        for (int r = 0; r < 4; r++) {
            int k = q * 4 + r;
#pragma unroll
            for (int c = 0; c < DOUT; c++) acc[c] = fmaf(vs[r], we[k * DOUT + c], acc[c]);
        }
    }
    if constexpr (DOUT == 4) {
        *(float4*)(out + (size_t)i * 4) = make_float4(acc[0], acc[1], acc[2], acc[3]);
    } else {
        *(float2*)(out + (size_t)i * 2) = make_float2(acc[0], acc[1]);
    }
}

// ---------------------------------------------------------------------------
extern "C" void kernel_launch(void* const* d_in, const int* in_sizes, int n_in,
                              void* d_out, int out_size, void* d_ws, size_t ws_size,
                              hipStream_t stream) {
    const float* x_bus = (const float*)d_in[0];
    const float* x_gen = (const float*)d_in[1];
    const int* src_bb = (const int*)d_in[2];
    const int* dst_bb = (const int*)d_in[3];
    const int* src_gb = (const int*)d_in[4];
    const int* dst_gb = (const int*)d_in[5];
    const int* src_bg = (const int*)d_in[6];
    const int* dst_bg = (const int*)d_in[7];
    const float* l1_bb_Wl = (const float*)d_in[8];
    const float* l1_bb_bl = (const float*)d_in[9];
    const float* l1_bb_Wr = (const float*)d_in[10];
    const float* l1_gb_Wl = (const float*)d_in[11];
    const float* l1_gb_bl = (const float*)d_in[12];
    const float* l1_gb_Wr = (const float*)d_in[13];
    const float* l1_bg_Wl = (const float*)d_in[14];
    const float* l1_bg_bl = (const float*)d_in[15];
    const float* l1_bg_Wr = (const float*)d_in[16];
    const float* l2_bb_Wl = (const float*)d_in[17];
    const float* l2_bb_bl = (const float*)d_in[18];
    const float* l2_bb_Wr = (const float*)d_in[19];
    const float* l2_gb_Wl = (const float*)d_in[20];
    const float* l2_gb_bl = (const float*)d_in[21];
    const float* l2_gb_Wr = (const float*)d_in[22];
    const float* l2_bg_Wl = (const float*)d_in[23];
    const float* l2_bg_bl = (const float*)d_in[24];
    const float* l2_bg_Wr = (const float*)d_in[25];
    const float* lin0_bus_W = (const float*)d_in[26];
    const float* lin0_bus_b = (const float*)d_in[27];
    const float* linf_bus_W = (const float*)d_in[28];
    const float* linf_bus_b = (const float*)d_in[29];
    const float* lin0_gen_W = (const float*)d_in[30];
    const float* lin0_gen_b = (const float*)d_in[31];
    const float* linf_gen_W = (const float*)d_in[32];
    const float* linf_gen_b = (const float*)d_in[33];

    // Workspace layout (~101 MB).
    char* ws = (char*)d_ws;
    size_t off = 0;
    auto alloc = [&](size_t bytes) {
        char* p = ws + off;
        off += (bytes + 255) & ~(size_t)255;
        return p;
    };
    unsigned* rs_bb = (unsigned*)alloc((size_t)N_BUS * 4);
    unsigned* rs_gb = (unsigned*)alloc((size_t)N_BUS * 4);
    unsigned* rs_bg = (unsigned*)alloc((size_t)N_GEN * 4);
    unsigned* cur_bb = (unsigned*)alloc(NBINS * 4);
    unsigned* cur_gb = (unsigned*)alloc(NBINS * 4);
    unsigned* cur_bg = (unsigned*)alloc(NBINS * 4);
    unsigned* e_bb = (unsigned*)alloc((size_t)E_BB * 4);
    unsigned* e_gb = (unsigned*)alloc((size_t)E_GB * 4);
    unsigned* e_bg = (unsigned*)alloc((size_t)E_BG * 4);
    float* y_bb = (float*)alloc((size_t)N_BUS * H * 4);
    float* y_bg = (float*)alloc((size_t)N_BUS * H * 4);
    float* y_gb = (float*)alloc((size_t)N_GEN * H * 4);
    float* h_bus = (float*)alloc((size_t)N_BUS * H * 4);
    float* h_gen = (float*)alloc((size_t)N_GEN * H * 4);
    float* W1b = (float*)alloc(64 * 96 * 4);
    float* B1b = (float*)alloc(96 * 4);
    float* W1g = (float*)alloc(64 * 64 * 4);
    float* B1g = (float*)alloc(64 * 4);
    float* W2b = (float*)alloc(32 * 96 * 4);
    float* B2b = (float*)alloc(96 * 4);
    float* W2g = (float*)alloc(32 * 64 * 4);
    float* B2g = (float*)alloc(64 * 4);

    // Pair buffers alias y_* (CSR build completes before transforms write y).
    unsigned* p_bb = (unsigned*)y_bb;  // 6.4 MB <= 25.6 MB
    unsigned* p_gb = (unsigned*)y_bg;  // 1.6 MB
    unsigned* p_bg = (unsigned*)y_gb;  // 1.6 MB

    // Fold weights (runs while CSR build saturates later).
    prep_kernel<<<32, 256, 0, stream>>>(
        l1_bb_Wl, l1_bb_bl, l1_bb_Wr, l1_gb_Wl, l1_gb_bl, l1_gb_Wr,
        l1_bg_Wl, l1_bg_bl, l1_bg_Wr, l2_bb_Wl, l2_bb_bl, l2_bb_Wr,
        l2_gb_Wl, l2_gb_bl, l2_gb_Wr, l2_bg_Wl, l2_bg_bl, l2_bg_Wr,
        W1b, B1b, W1g, B1g, W2b, B2b, W2g, B2g);

    // cursors are contiguous: one memset.
    hipMemsetAsync(cur_bb, 0, 3 * NBINS * 4, stream);

    auto build_csr = [&](const int* src, const int* dst, int nE, int nDst,
                         unsigned* cur, unsigned* pairs, unsigned* rs, unsigned* esrc) {
        int hb = (nE + 255) / 256; if (hb > 256) hb = 256;
        coarse_hist_kernel<<<hb, 256, 0, stream>>>(dst, nE, cur);
        scan1024_kernel<<<1, 256, 0, stream>>>(cur);
        partition_kernel<<<(nE + 256 * EPT - 1) / (256 * EPT), 256, 0, stream>>>(src, dst, nE, cur, pairs);
        fine_csr_kernel<<<(nDst + 255) / 256, 256, 0, stream>>>(cur, pairs, rs, esrc, nDst);
    };
    build_csr(src_bb, dst_bb, E_BB, N_BUS, cur_bb, p_bb, rs_bb, e_bb);
    build_csr(src_gb, dst_gb, E_GB, N_BUS, cur_gb, p_gb, rs_gb, e_gb);
    build_csr(src_bg, dst_bg, E_BG, N_GEN, cur_bg, p_bg, rs_bg, e_bg);

    const int gb_bus = (N_BUS + 255) / 256;
    const int gb_gen = (N_GEN + 255) / 256;
    const int gp_bus = (N_BUS * 8 + 255) / 256;
    const int gp_gen = (N_GEN * 8 + 255) / 256;

    // ---- Layer 1 ----
    transform2_kernel<64, 96, false><<<gb_bus, 256, 0, stream>>>(
        x_bus, N_BUS, W1b, B1b, y_bb, y_bg, h_bus);
    transform2_kernel<64, 64, false><<<gb_gen, 256, 0, stream>>>(
        x_gen, N_GEN, W1g, B1g, y_gb, nullptr, h_gen);
    pull_kernel<true><<<gp_bus, 256, 0, stream>>>(rs_bb, e_bb, y_bb, rs_gb, e_gb, y_gb, h_bus, N_BUS);
    pull_kernel<false><<<gp_gen, 256, 0, stream>>>(rs_bg, e_bg, y_bg, nullptr, nullptr, nullptr, h_gen, N_GEN);

    // ---- Layer 2 (relu on load; root written in-place over h_*) ----
    transform2_kernel<32, 96, true><<<gb_bus, 256, 0, stream>>>(
        h_bus, N_BUS, W2b, B2b, y_bb, y_bg, h_bus);
    transform2_kernel<32, 64, true><<<gb_gen, 256, 0, stream>>>(
        h_gen, N_GEN, W2g, B2g, y_gb, nullptr, h_gen);
    pull_kernel<true><<<gp_bus, 256, 0, stream>>>(rs_bb, e_bb, y_bb, rs_gb, e_gb, y_gb, h_bus, N_BUS);
    pull_kernel<false><<<gp_gen, 256, 0, stream>>>(rs_bg, e_bg, y_bg, nullptr, nullptr, nullptr, h_gen, N_GEN);

    // ---- Head ----
    final_kernel<4><<<gb_bus, 256, 0, stream>>>(h_bus, N_BUS, lin0_bus_W, lin0_bus_b,
                                                linf_bus_W, linf_bus_b, (float*)d_out);
    final_kernel<2><<<gb_gen, 256, 0, stream>>>(h_gen, N_GEN, lin0_gen_W, lin0_gen_b,
                                                linf_gen_W, linf_gen_b, (float*)d_out + (size_t)N_BUS * 4);
}